// Round 3
// baseline (265.750 us; speedup 1.0000x reference)
//
#include <hip/hip_runtime.h>
#include <stdint.h>

typedef __bf16 bf16;
typedef __bf16 bf16x8 __attribute__((ext_vector_type(8)));
typedef __bf16 bf16x4 __attribute__((ext_vector_type(4)));
typedef float f32x4 __attribute__((ext_vector_type(4)));
typedef unsigned short u16x8 __attribute__((ext_vector_type(8)));

#define B_    8
#define C_    512
#define N_    4096
#define OC2_  512
#define KC_   256

typedef __attribute__((address_space(1))) const uint32_t* gas1_t;
typedef __attribute__((address_space(3))) uint32_t* las3_t;

__device__ __forceinline__ void gload16(const void* g, void* l) {
  __builtin_amdgcn_global_load_lds((gas1_t)g, (las3_t)l, 16, 0, 0);
}

// ---------------- prep: fold BN, cast weights to bf16 ----------------
__global__ __launch_bounds__(256) void prep_kernel(
    const float* __restrict__ fk_cw, const float* __restrict__ fk_cb,
    const float* __restrict__ fk_bg, const float* __restrict__ fk_bb,
    const float* __restrict__ fk_bm, const float* __restrict__ fk_bv,
    const float* __restrict__ fk_dw, const float* __restrict__ fk_db,
    const float* __restrict__ fk_dg, const float* __restrict__ fk_dbb,
    const float* __restrict__ fk_dm, const float* __restrict__ fk_dv,
    const float* __restrict__ fv_cw, const float* __restrict__ fv_cb,
    const float* __restrict__ fv_bg, const float* __restrict__ fv_bb,
    const float* __restrict__ fv_bm, const float* __restrict__ fv_bv,
    const float* __restrict__ fv_dw, const float* __restrict__ fv_db,
    const float* __restrict__ fv_dg, const float* __restrict__ fv_dbb,
    const float* __restrict__ fv_dm, const float* __restrict__ fv_dv,
    const float* __restrict__ w_w,
    bf16* __restrict__ Wcat, bf16* __restrict__ Ww,
    float* __restrict__ sconv, float* __restrict__ tconv,
    float* __restrict__ wdw9, float* __restrict__ tdw)
{
  int i = blockIdx.x * 256 + threadIdx.x;
  if (i < 262144) {                       // Wcat [512][512] bf16
    int oc = i >> 9, c = i & 511;
    float v = (oc < 256) ? fk_cw[oc * 512 + c] : fv_cw[(oc - 256) * 512 + c];
    Wcat[i] = (bf16)v;
  } else if (i < 393216) {                // Ww [512][256] bf16
    int j = i - 262144;
    Ww[j] = (bf16)w_w[j];
  } else if (i < 393728) {                // conv-BN fold
    int oc = i - 393216;
    float g, bb, m, v, cb;
    if (oc < 256) { g = fk_bg[oc]; bb = fk_bb[oc]; m = fk_bm[oc]; v = fk_bv[oc]; cb = fk_cb[oc]; }
    else { int c2 = oc - 256; g = fv_bg[c2]; bb = fv_bb[c2]; m = fv_bm[c2]; v = fv_bv[c2]; cb = fv_cb[c2]; }
    float s = g / sqrtf(v + 1e-5f);
    sconv[oc] = s;
    tconv[oc] = cb * s + bb - m * s;
  } else if (i < 394240) {                // dwconv-BN fold
    int oc = i - 393728;
    float g, bb, m, v, db;
    const float* dwp;
    if (oc < 256) { g = fk_dg[oc]; bb = fk_dbb[oc]; m = fk_dm[oc]; v = fk_dv[oc]; db = fk_db[oc]; dwp = fk_dw + oc * 9; }
    else { int c2 = oc - 256; g = fv_dg[c2]; bb = fv_dbb[c2]; m = fv_dm[c2]; v = fv_dv[c2]; db = fv_db[c2]; dwp = fv_dw + c2 * 9; }
    float s2 = g / sqrtf(v + 1e-5f);
    for (int j = 0; j < 9; ++j) wdw9[oc * 9 + j] = dwp[j] * s2;
    tdw[oc] = db * s2 + bb - m * s2;
  }
}

// ---------------- k0: x [B,C,N] fp32 -> xb [B,N,C] bf16 (tiled transpose) ----
__global__ __launch_bounds__(256) void k0_transpose(const float* __restrict__ x,
                                                    bf16* __restrict__ xb)
{
  __shared__ float t[64 * 64];
  int nt = blockIdx.x, ct = blockIdx.y, b = blockIdx.z;
  int tid = threadIdx.x;
  const float* src = x + ((size_t)(b * C_ + ct * 64)) * N_ + nt * 64;
#pragma unroll
  for (int i = 0; i < 4; ++i) {
    int chunk = tid + i * 256;            // 64 rows(c) x 16 float4
    int c = chunk >> 4, c4 = chunk & 15;
    float4 v = *(const float4*)(src + (size_t)c * N_ + c4 * 4);
    int n0 = c4 * 4, k = c & 31;
    t[c * 64 + ((n0 + 0) ^ k)] = v.x;
    t[c * 64 + ((n0 + 1) ^ k)] = v.y;
    t[c * 64 + ((n0 + 2) ^ k)] = v.z;
    t[c * 64 + ((n0 + 3) ^ k)] = v.w;
  }
  __syncthreads();
  bf16* dst = xb + ((size_t)b * N_ + nt * 64) * C_ + ct * 64;
#pragma unroll
  for (int i = 0; i < 2; ++i) {
    int u = tid + i * 256;                // 64 n x 8 c-chunks
    int nl = u >> 3, c8 = u & 7;
    bf16x8 o;
#pragma unroll
    for (int j = 0; j < 8; ++j) {
      int cc = c8 * 8 + j;
      o[j] = (bf16)t[cc * 64 + (nl ^ (cc & 31))];
    }
    *(bf16x8*)(dst + (size_t)nl * C_ + c8 * 8) = o;
  }
}

// ---------------- common TN GEMM: A[M][K] rm, B^T[N][K] rm, 128x128x64 tiles --
// EPI: 0 = y=acc*s[gm]+t[gm] -> bf16 ; 1 = atomicAdd(fp32, acc/64)
//      2 = bf16 store        ; 3 = fp32 store + e0[gm] bias
template<int EPI, int MTILES, int NTILES, int KSPLIT, int KCHUNK>
__global__ __launch_bounds__(256, 2) void gemm_tn(
    const bf16* __restrict__ A, int lda, size_t sA,
    const bf16* __restrict__ Bm, int ldb, size_t sB,
    void* __restrict__ Cv, int ldc, size_t sC,
    const float* __restrict__ e0, const float* __restrict__ e1)
{
  __shared__ bf16 As[128 * 64];
  __shared__ bf16 Bs[128 * 64];
  int bid = blockIdx.x;
  int ks  = bid % KSPLIT; bid /= KSPLIT;
  int ntl = bid % NTILES; bid /= NTILES;
  int mtl = bid % MTILES; bid /= MTILES;
  int b = bid;
  const bf16* Ab = A  + (size_t)b * sA + (size_t)mtl * 128 * lda + ks * KCHUNK;
  const bf16* Bb = Bm + (size_t)b * sB + (size_t)ntl * 128 * ldb + ks * KCHUNK;
  int tid = threadIdx.x;
  int lane = tid & 63, w = tid >> 6;
  int mb = (w >> 1) * 64, nb = (w & 1) * 64;
  int lrow = lane & 15, lk = (lane >> 4) * 8;

  f32x4 acc[4][4];
#pragma unroll
  for (int i = 0; i < 4; ++i)
#pragma unroll
    for (int j = 0; j < 4; ++j) acc[i][j] = 0.f;

  for (int kt = 0; kt < KCHUNK / 64; ++kt) {
    __syncthreads();
#pragma unroll
    for (int i = 0; i < 4; ++i) {
      int chunk = tid + i * 256;          // 128 rows x 8 16B-chunks
      int row = chunk >> 3, c8 = chunk & 7;
      gload16(Ab + (size_t)row * lda + kt * 64 + c8 * 8, &As[chunk * 8]);
      gload16(Bb + (size_t)row * ldb + kt * 64 + c8 * 8, &Bs[chunk * 8]);
    }
    __syncthreads();
#pragma unroll
    for (int kk = 0; kk < 2; ++kk) {
      bf16x8 af[4], bfr[4];
#pragma unroll
      for (int mi = 0; mi < 4; ++mi)
        af[mi] = *reinterpret_cast<const bf16x8*>(&As[(mb + mi * 16 + lrow) * 64 + kk * 32 + lk]);
#pragma unroll
      for (int ni = 0; ni < 4; ++ni)
        bfr[ni] = *reinterpret_cast<const bf16x8*>(&Bs[(nb + ni * 16 + lrow) * 64 + kk * 32 + lk]);
#pragma unroll
      for (int mi = 0; mi < 4; ++mi)
#pragma unroll
        for (int ni = 0; ni < 4; ++ni)
          acc[mi][ni] = __builtin_amdgcn_mfma_f32_16x16x32_bf16(af[mi], bfr[ni], acc[mi][ni], 0, 0, 0);
    }
  }

  int col = lane & 15, r0 = (lane >> 4) * 4;
#pragma unroll
  for (int mi = 0; mi < 4; ++mi) {
#pragma unroll
    for (int ni = 0; ni < 4; ++ni) {
#pragma unroll
      for (int r = 0; r < 4; ++r) {
        int gm = mtl * 128 + mb + mi * 16 + r0 + r;
        int gn = ntl * 128 + nb + ni * 16 + col;
        float v = acc[mi][ni][r];
        size_t o = (size_t)b * sC + (size_t)gm * ldc + gn;
        if constexpr (EPI == 0)      ((bf16*)Cv)[o] = (bf16)(v * e0[gm] + e1[gm]);
        else if constexpr (EPI == 1) atomicAdd(&((float*)Cv)[o], v * 0.015625f);
        else if constexpr (EPI == 2) ((bf16*)Cv)[o] = (bf16)v;
        else                         ((float*)Cv)[o] = v + e0[gm];
      }
    }
  }
}

// ---------------- k2: depthwise 3x3 + BN + FReLU (per-channel 64x64 plane) ---
__global__ __launch_bounds__(256) void k2_dwfrelu(
    const bf16* __restrict__ y, const float* __restrict__ wdw9,
    const float* __restrict__ tdw, bf16* __restrict__ kf, bf16* __restrict__ vfc)
{
  __shared__ bf16 pl[66 * 66];            // stride 66, rows 0 & 65 are zero halo
  int ch = blockIdx.x, b = blockIdx.y;
  int tid = threadIdx.x;
  if (tid < 66) { pl[tid] = (bf16)0.f; pl[65 * 66 + tid] = (bf16)0.f; }
  const bf16* src = y + ((size_t)(b * OC2_ + ch)) * N_;
#pragma unroll
  for (int i = 0; i < 2; ++i) {
    int u = tid + i * 256;                // 64 rows x 8 chunks of 8
    int r = u >> 3, c8 = u & 7;
    uint4 d = *(const uint4*)(src + (size_t)r * 64 + c8 * 8);
    uint32_t* lp = (uint32_t*)&pl[(r + 1) * 66 + c8 * 8];
    lp[0] = d.x; lp[1] = d.y; lp[2] = d.z; lp[3] = d.w;
  }
  __syncthreads();
  float wf[9];
#pragma unroll
  for (int j = 0; j < 9; ++j) wf[j] = wdw9[ch * 9 + j];
  float tb = tdw[ch];
  int r = tid >> 2, ws0 = (tid & 3) * 16;
  float row0[18], row1[18], row2[18];
#pragma unroll
  for (int j = 0; j < 18; ++j) {
    int c = ws0 + j - 1;
    bool ok = (c >= 0) && (c < 64);
    row0[j] = ok ? (float)pl[(r + 0) * 66 + c] : 0.f;
    row1[j] = ok ? (float)pl[(r + 1) * 66 + c] : 0.f;
    row2[j] = ok ? (float)pl[(r + 2) * 66 + c] : 0.f;
  }
  bf16x8 o0, o1;
#pragma unroll
  for (int wi = 0; wi < 16; ++wi) {
    float a = row0[wi] * wf[0] + row0[wi + 1] * wf[1] + row0[wi + 2] * wf[2]
            + row1[wi] * wf[3] + row1[wi + 1] * wf[4] + row1[wi + 2] * wf[5]
            + row2[wi] * wf[6] + row2[wi + 1] * wf[7] + row2[wi + 2] * wf[8] + tb;
    float z = fmaxf(row1[wi + 1], a);
    if (wi < 8) o0[wi] = (bf16)z; else o1[wi - 8] = (bf16)z;
  }
  bf16* dst = (ch < KC_) ? (kf + ((size_t)(b * KC_ + ch)) * N_)
                         : (vfc + ((size_t)(b * KC_ + ch - KC_)) * N_);
  *(bf16x8*)(dst + (size_t)r * 64 + ws0) = o0;
  *(bf16x8*)(dst + (size_t)r * 64 + ws0 + 8) = o1;
}

// ---------------- k2b: vf [B,256,N] -> [B,N,256] bf16 transpose --------------
__global__ __launch_bounds__(256) void k2b_transpose(const bf16* __restrict__ vfc,
                                                     bf16* __restrict__ vfh)
{
  __shared__ uint32_t t[64 * 64];
  int nt = blockIdx.x, vt = blockIdx.y, b = blockIdx.z;
  int tid = threadIdx.x;
  const uint16_t* src = (const uint16_t*)(vfc + ((size_t)(b * KC_ + vt * 64)) * N_ + nt * 64);
#pragma unroll
  for (int i = 0; i < 2; ++i) {
    int u = tid + i * 256;
    int v = u >> 3, c8 = u & 7;
    u16x8 d = *(const u16x8*)(src + (size_t)v * N_ + c8 * 8);
#pragma unroll
    for (int j = 0; j < 8; ++j) {
      int n = c8 * 8 + j;
      t[v * 64 + (n ^ (v & 31))] = d[j];
    }
  }
  __syncthreads();
  uint16_t* dst = (uint16_t*)(vfh + ((size_t)b * N_ + nt * 64) * KC_ + vt * 64);
#pragma unroll
  for (int i = 0; i < 2; ++i) {
    int u = tid + i * 256;
    int nl = u >> 3, v8 = u & 7;
    u16x8 o;
#pragma unroll
    for (int j = 0; j < 8; ++j) {
      int v = v8 * 8 + j;
      o[j] = (uint16_t)t[v * 64 + (nl ^ (v & 31))];
    }
    *(u16x8*)(dst + (size_t)nl * KC_ + v8 * 8) = o;
  }
}

// ---------------- softmax over rows of sim [2048][256] -> P bf16 -------------
__global__ __launch_bounds__(256) void softmax_k(const float* __restrict__ sim,
                                                 bf16* __restrict__ P)
{
  int row = blockIdx.x * 4 + (threadIdx.x >> 6);
  int lane = threadIdx.x & 63;
  float4 v = ((const float4*)(sim + (size_t)row * 256))[lane];
  float mx = fmaxf(fmaxf(v.x, v.y), fmaxf(v.z, v.w));
#pragma unroll
  for (int s = 32; s; s >>= 1) mx = fmaxf(mx, __shfl_xor(mx, s));
  float a0 = __expf(v.x - mx), a1 = __expf(v.y - mx);
  float a2 = __expf(v.z - mx), a3 = __expf(v.w - mx);
  float sm = a0 + a1 + a2 + a3;
#pragma unroll
  for (int s = 32; s; s >>= 1) sm += __shfl_xor(sm, s);
  float inv = 1.0f / sm;
  bf16x4 o;
  o[0] = (bf16)(a0 * inv); o[1] = (bf16)(a1 * inv);
  o[2] = (bf16)(a2 * inv); o[3] = (bf16)(a3 * inv);
  *(bf16x4*)(P + (size_t)row * 256 + lane * 4) = o;
}

// ---------------- host launch ------------------------------------------------
extern "C" void kernel_launch(void* const* d_in, const int* in_sizes, int n_in,
                              void* d_out, int out_size, void* d_ws, size_t ws_size,
                              hipStream_t stream) {
  const float* x      = (const float*)d_in[0];
  const float* fk_cw  = (const float*)d_in[1];
  const float* fk_cb  = (const float*)d_in[2];
  const float* fk_bg  = (const float*)d_in[3];
  const float* fk_bb  = (const float*)d_in[4];
  const float* fk_bm  = (const float*)d_in[5];
  const float* fk_bv  = (const float*)d_in[6];
  const float* fk_dw  = (const float*)d_in[7];
  const float* fk_db  = (const float*)d_in[8];
  const float* fk_dg  = (const float*)d_in[9];
  const float* fk_dbb = (const float*)d_in[10];
  const float* fk_dm  = (const float*)d_in[11];
  const float* fk_dv  = (const float*)d_in[12];
  const float* fv_cw  = (const float*)d_in[13];
  const float* fv_cb  = (const float*)d_in[14];
  const float* fv_bg  = (const float*)d_in[15];
  const float* fv_bb  = (const float*)d_in[16];
  const float* fv_bm  = (const float*)d_in[17];
  const float* fv_bv  = (const float*)d_in[18];
  const float* fv_dw  = (const float*)d_in[19];
  const float* fv_db  = (const float*)d_in[20];
  const float* fv_dg  = (const float*)d_in[21];
  const float* fv_dbb = (const float*)d_in[22];
  const float* fv_dm  = (const float*)d_in[23];
  const float* fv_dv  = (const float*)d_in[24];
  const float* w_w    = (const float*)d_in[25];
  const float* w_b    = (const float*)d_in[26];

  char* wsp = (char*)d_ws;
  size_t off = 0;
  auto take = [&](size_t bytes) -> void* {
    void* p = wsp + off;
    off += (bytes + 255) & ~(size_t)255;
    return p;
  };
  bf16*  xb    = (bf16*) take((size_t)B_ * N_ * C_ * 2);      // 33.6 MB  x NHWC bf16 (later reused as vfh)
  bf16*  y     = (bf16*) take((size_t)B_ * OC2_ * N_ * 2);    // 33.6 MB  conv+BN out NCHW
  bf16*  kf    = (bf16*) take((size_t)B_ * KC_ * N_ * 2);     // 16.8 MB  key-branch NCHW
  bf16*  vfc   = (bf16*) take((size_t)B_ * KC_ * N_ * 2);     // 16.8 MB  value-branch NCHW
  float* sim   = (float*)take((size_t)B_ * KC_ * KC_ * 4);    //  2.1 MB
  bf16*  P     = (bf16*) take((size_t)B_ * KC_ * KC_ * 2);    //  1.0 MB
  bf16*  MmT   = (bf16*) take((size_t)B_ * 512 * KC_ * 2);    //  2.1 MB  (P @ Ww^T)^T
  bf16*  Wcat  = (bf16*) take((size_t)512 * 512 * 2);
  bf16*  Ww    = (bf16*) take((size_t)512 * 256 * 2);
  float* sconv = (float*)take(512 * 4);
  float* tconv = (float*)take(512 * 4);
  float* wdw9  = (float*)take(512 * 9 * 4);
  float* tdwb  = (float*)take(512 * 4);
  // vfh aliases xb: xb is only read by the branch-conv GEMM; vfh is first
  // written by k2b_transpose, which runs strictly after that GEMM.
  bf16*  vfh   = xb;                                          // 16.8 MB  value-branch NHWC

  prep_kernel<<<1540, 256, 0, stream>>>(
      fk_cw, fk_cb, fk_bg, fk_bb, fk_bm, fk_bv, fk_dw, fk_db, fk_dg, fk_dbb, fk_dm, fk_dv,
      fv_cw, fv_cb, fv_bg, fv_bb, fv_bm, fv_bv, fv_dw, fv_db, fv_dg, fv_dbb, fv_dm, fv_dv,
      w_w, Wcat, Ww, sconv, tconv, wdw9, tdwb);

  k0_transpose<<<dim3(64, 8, 8), 256, 0, stream>>>(x, xb);

  // y[b,oc,n] = BN(Wcat @ xb) : M=512 oc, N=4096 n, K=512 c
  gemm_tn<0, 4, 32, 1, 512><<<dim3(1024), 256, 0, stream>>>(
      Wcat, 512, 0, xb, 512, (size_t)N_ * C_, y, 4096, (size_t)OC2_ * N_, sconv, tconv);

  k2_dwfrelu<<<dim3(512, 8), 256, 0, stream>>>(y, wdw9, tdwb, kf, vfc);
  k2b_transpose<<<dim3(64, 4, 8), 256, 0, stream>>>(vfc, vfh);

  hipMemsetAsync(sim, 0, (size_t)B_ * KC_ * KC_ * 4, stream);
  // sim[b,v,k] = (vf . kf over n)/64 : split-K=8, fp32 atomic accumulate
  gemm_tn<1, 2, 2, 8, 512><<<dim3(256), 256, 0, stream>>>(
      vfc, 4096, (size_t)KC_ * N_, kf, 4096, (size_t)KC_ * N_,
      sim, 256, (size_t)KC_ * KC_, nullptr, nullptr);

  softmax_k<<<dim3(512), 256, 0, stream>>>(sim, P);

  // MmT[b,o,v] = sum_k Ww[o,k] P[v,k]
  gemm_tn<2, 4, 2, 1, 256><<<dim3(64), 256, 0, stream>>>(
      Ww, 256, 0, P, 256, (size_t)KC_ * KC_,
      MmT, 256, (size_t)512 * KC_, nullptr, nullptr);

  // out[b,o,n] = sum_v MmT[o,v] vfh[n,v] + w_b[o]
  gemm_tn<3, 4, 32, 1, 256><<<dim3(1024), 256, 0, stream>>>(
      MmT, 256, (size_t)512 * KC_, vfh, 256, (size_t)N_ * KC_,
      (float*)d_out, 4096, (size_t)512 * N_, w_b, nullptr);
}

// Round 4
// 262.653 us; speedup vs baseline: 1.0118x; 1.0118x over previous
//
#include <hip/hip_runtime.h>
#include <stdint.h>

typedef __bf16 bf16;
typedef __bf16 bf16x8 __attribute__((ext_vector_type(8)));
typedef __bf16 bf16x4 __attribute__((ext_vector_type(4)));
typedef float f32x4 __attribute__((ext_vector_type(4)));
typedef unsigned short u16x8 __attribute__((ext_vector_type(8)));

#define B_    8
#define C_    512
#define N_    4096
#define OC2_  512
#define KC_   256

typedef __attribute__((address_space(1))) const uint32_t* gas1_t;
typedef __attribute__((address_space(3))) uint32_t* las3_t;

__device__ __forceinline__ void gload16(const void* g, void* l) {
  __builtin_amdgcn_global_load_lds((gas1_t)g, (las3_t)l, 16, 0, 0);
}

// ---------------- prep: fold BN, cast weights to bf16 ----------------
__global__ __launch_bounds__(256) void prep_kernel(
    const float* __restrict__ fk_cw, const float* __restrict__ fk_cb,
    const float* __restrict__ fk_bg, const float* __restrict__ fk_bb,
    const float* __restrict__ fk_bm, const float* __restrict__ fk_bv,
    const float* __restrict__ fk_dw, const float* __restrict__ fk_db,
    const float* __restrict__ fk_dg, const float* __restrict__ fk_dbb,
    const float* __restrict__ fk_dm, const float* __restrict__ fk_dv,
    const float* __restrict__ fv_cw, const float* __restrict__ fv_cb,
    const float* __restrict__ fv_bg, const float* __restrict__ fv_bb,
    const float* __restrict__ fv_bm, const float* __restrict__ fv_bv,
    const float* __restrict__ fv_dw, const float* __restrict__ fv_db,
    const float* __restrict__ fv_dg, const float* __restrict__ fv_dbb,
    const float* __restrict__ fv_dm, const float* __restrict__ fv_dv,
    const float* __restrict__ w_w,
    bf16* __restrict__ Wcat, bf16* __restrict__ Ww,
    float* __restrict__ sconv, float* __restrict__ tconv,
    float* __restrict__ wdw9, float* __restrict__ tdw)
{
  int i = blockIdx.x * 256 + threadIdx.x;
  if (i < 262144) {                       // Wcat [512][512] bf16
    int oc = i >> 9, c = i & 511;
    float v = (oc < 256) ? fk_cw[oc * 512 + c] : fv_cw[(oc - 256) * 512 + c];
    Wcat[i] = (bf16)v;
  } else if (i < 393216) {                // Ww [512][256] bf16
    int j = i - 262144;
    Ww[j] = (bf16)w_w[j];
  } else if (i < 393728) {                // conv-BN fold
    int oc = i - 393216;
    float g, bb, m, v, cb;
    if (oc < 256) { g = fk_bg[oc]; bb = fk_bb[oc]; m = fk_bm[oc]; v = fk_bv[oc]; cb = fk_cb[oc]; }
    else { int c2 = oc - 256; g = fv_bg[c2]; bb = fv_bb[c2]; m = fv_bm[c2]; v = fv_bv[c2]; cb = fv_cb[c2]; }
    float s = g / sqrtf(v + 1e-5f);
    sconv[oc] = s;
    tconv[oc] = cb * s + bb - m * s;
  } else if (i < 394240) {                // dwconv-BN fold
    int oc = i - 393728;
    float g, bb, m, v, db;
    const float* dwp;
    if (oc < 256) { g = fk_dg[oc]; bb = fk_dbb[oc]; m = fk_dm[oc]; v = fk_dv[oc]; db = fk_db[oc]; dwp = fk_dw + oc * 9; }
    else { int c2 = oc - 256; g = fv_dg[c2]; bb = fv_dbb[c2]; m = fv_dm[c2]; v = fv_dv[c2]; db = fv_db[c2]; dwp = fv_dw + c2 * 9; }
    float s2 = g / sqrtf(v + 1e-5f);
    for (int j = 0; j < 9; ++j) wdw9[oc * 9 + j] = dwp[j] * s2;
    tdw[oc] = db * s2 + bb - m * s2;
  }
}

// ---------------- k0: x [B,C,N] fp32 -> xb [B,N,C] bf16 (tiled transpose) ----
__global__ __launch_bounds__(256) void k0_transpose(const float* __restrict__ x,
                                                    bf16* __restrict__ xb)
{
  __shared__ float t[64 * 64];
  int nt = blockIdx.x, ct = blockIdx.y, b = blockIdx.z;
  int tid = threadIdx.x;
  const float* src = x + ((size_t)(b * C_ + ct * 64)) * N_ + nt * 64;
#pragma unroll
  for (int i = 0; i < 4; ++i) {
    int chunk = tid + i * 256;            // 64 rows(c) x 16 float4
    int c = chunk >> 4, c4 = chunk & 15;
    float4 v = *(const float4*)(src + (size_t)c * N_ + c4 * 4);
    int n0 = c4 * 4, k = c & 31;
    t[c * 64 + ((n0 + 0) ^ k)] = v.x;
    t[c * 64 + ((n0 + 1) ^ k)] = v.y;
    t[c * 64 + ((n0 + 2) ^ k)] = v.z;
    t[c * 64 + ((n0 + 3) ^ k)] = v.w;
  }
  __syncthreads();
  bf16* dst = xb + ((size_t)b * N_ + nt * 64) * C_ + ct * 64;
#pragma unroll
  for (int i = 0; i < 2; ++i) {
    int u = tid + i * 256;                // 64 n x 8 c-chunks
    int nl = u >> 3, c8 = u & 7;
    bf16x8 o;
#pragma unroll
    for (int j = 0; j < 8; ++j) {
      int cc = c8 * 8 + j;
      o[j] = (bf16)t[cc * 64 + (nl ^ (cc & 31))];
    }
    *(bf16x8*)(dst + (size_t)nl * C_ + c8 * 8) = o;
  }
}

// ---------------- common TN GEMM: A[M][K] rm, B^T[N][K] rm, 128x128x64 tiles --
// EPI: 0 = y=acc*s[gm]+t[gm] -> bf16 ; 2 = bf16 store
//      3 = fp32 store + e0[gm] bias   ; 4 = fp32 partial store to [b*KSPLIT+ks]
template<int EPI, int MTILES, int NTILES, int KSPLIT, int KCHUNK>
__global__ __launch_bounds__(256, 2) void gemm_tn(
    const bf16* __restrict__ A, int lda, size_t sA,
    const bf16* __restrict__ Bm, int ldb, size_t sB,
    void* __restrict__ Cv, int ldc, size_t sC,
    const float* __restrict__ e0, const float* __restrict__ e1)
{
  __shared__ bf16 As[128 * 64];
  __shared__ bf16 Bs[128 * 64];
  int bid = blockIdx.x;
  int ks  = bid % KSPLIT; bid /= KSPLIT;
  int ntl = bid % NTILES; bid /= NTILES;
  int mtl = bid % MTILES; bid /= MTILES;
  int b = bid;
  const bf16* Ab = A  + (size_t)b * sA + (size_t)mtl * 128 * lda + ks * KCHUNK;
  const bf16* Bb = Bm + (size_t)b * sB + (size_t)ntl * 128 * ldb + ks * KCHUNK;
  int tid = threadIdx.x;
  int lane = tid & 63, w = tid >> 6;
  int mb = (w >> 1) * 64, nb = (w & 1) * 64;
  int lrow = lane & 15, lk = (lane >> 4) * 8;

  f32x4 acc[4][4];
#pragma unroll
  for (int i = 0; i < 4; ++i)
#pragma unroll
    for (int j = 0; j < 4; ++j) acc[i][j] = 0.f;

  for (int kt = 0; kt < KCHUNK / 64; ++kt) {
    __syncthreads();
#pragma unroll
    for (int i = 0; i < 4; ++i) {
      int chunk = tid + i * 256;          // 128 rows x 8 16B-chunks
      int row = chunk >> 3, c8 = chunk & 7;
      gload16(Ab + (size_t)row * lda + kt * 64 + c8 * 8, &As[chunk * 8]);
      gload16(Bb + (size_t)row * ldb + kt * 64 + c8 * 8, &Bs[chunk * 8]);
    }
    __syncthreads();
#pragma unroll
    for (int kk = 0; kk < 2; ++kk) {
      bf16x8 af[4], bfr[4];
#pragma unroll
      for (int mi = 0; mi < 4; ++mi)
        af[mi] = *reinterpret_cast<const bf16x8*>(&As[(mb + mi * 16 + lrow) * 64 + kk * 32 + lk]);
#pragma unroll
      for (int ni = 0; ni < 4; ++ni)
        bfr[ni] = *reinterpret_cast<const bf16x8*>(&Bs[(nb + ni * 16 + lrow) * 64 + kk * 32 + lk]);
#pragma unroll
      for (int mi = 0; mi < 4; ++mi)
#pragma unroll
        for (int ni = 0; ni < 4; ++ni)
          acc[mi][ni] = __builtin_amdgcn_mfma_f32_16x16x32_bf16(af[mi], bfr[ni], acc[mi][ni], 0, 0, 0);
    }
  }

  int col = lane & 15, r0 = (lane >> 4) * 4;
#pragma unroll
  for (int mi = 0; mi < 4; ++mi) {
#pragma unroll
    for (int ni = 0; ni < 4; ++ni) {
#pragma unroll
      for (int r = 0; r < 4; ++r) {
        int gm = mtl * 128 + mb + mi * 16 + r0 + r;
        int gn = ntl * 128 + nb + ni * 16 + col;
        float v = acc[mi][ni][r];
        if constexpr (EPI == 4) {
          // partial store: slab (b*KSPLIT + ks), stride sC elements
          ((float*)Cv)[((size_t)b * KSPLIT + ks) * sC + (size_t)gm * ldc + gn] = v * 0.015625f;
        } else {
          size_t o = (size_t)b * sC + (size_t)gm * ldc + gn;
          if constexpr (EPI == 0)      ((bf16*)Cv)[o] = (bf16)(v * e0[gm] + e1[gm]);
          else if constexpr (EPI == 2) ((bf16*)Cv)[o] = (bf16)v;
          else                         ((float*)Cv)[o] = v + e0[gm];
        }
      }
    }
  }
}

// ---------------- k2: depthwise 3x3 + BN + FReLU (per-channel 64x64 plane) ---
__global__ __launch_bounds__(256) void k2_dwfrelu(
    const bf16* __restrict__ y, const float* __restrict__ wdw9,
    const float* __restrict__ tdw, bf16* __restrict__ kf, bf16* __restrict__ vfc)
{
  __shared__ bf16 pl[66 * 72];            // stride 72 (16B-aligned rows); rows 0 & 65 zero halo
  int ch = blockIdx.x, b = blockIdx.y;
  int tid = threadIdx.x;
  if (tid < 72) { pl[tid] = (bf16)0.f; pl[65 * 72 + tid] = (bf16)0.f; }
  const bf16* src = y + ((size_t)(b * OC2_ + ch)) * N_;
#pragma unroll
  for (int i = 0; i < 2; ++i) {
    int u = tid + i * 256;                // 64 rows x 8 chunks of 8
    int r = u >> 3, c8 = u & 7;
    uint4 d = *(const uint4*)(src + (size_t)r * 64 + c8 * 8);
    uint32_t* lp = (uint32_t*)&pl[(r + 1) * 72 + c8 * 8];
    lp[0] = d.x; lp[1] = d.y; lp[2] = d.z; lp[3] = d.w;
  }
  __syncthreads();
  float wf[9];
#pragma unroll
  for (int j = 0; j < 9; ++j) wf[j] = wdw9[ch * 9 + j];
  float tb = tdw[ch];
  int r = tid >> 2, ws0 = (tid & 3) * 16;
  // window cols [ws0-1, ws0+16] of plane rows r-1..r+1 (= padded rows r..r+2)
  float win[3][18];
#pragma unroll
  for (int row = 0; row < 3; ++row) {
    const bf16* rp = &pl[(r + row) * 72];
    bf16x8 v0 = *reinterpret_cast<const bf16x8*>(rp + ws0);
    bf16x8 v1 = *reinterpret_cast<const bf16x8*>(rp + ws0 + 8);
    win[row][0]  = (ws0 > 0)  ? (float)rp[ws0 - 1]  : 0.f;
    win[row][17] = (ws0 < 48) ? (float)rp[ws0 + 16] : 0.f;
#pragma unroll
    for (int j = 0; j < 8; ++j) { win[row][1 + j] = (float)v0[j]; win[row][9 + j] = (float)v1[j]; }
  }
  bf16x8 o0, o1;
#pragma unroll
  for (int wi = 0; wi < 16; ++wi) {
    float a = win[0][wi] * wf[0] + win[0][wi + 1] * wf[1] + win[0][wi + 2] * wf[2]
            + win[1][wi] * wf[3] + win[1][wi + 1] * wf[4] + win[1][wi + 2] * wf[5]
            + win[2][wi] * wf[6] + win[2][wi + 1] * wf[7] + win[2][wi + 2] * wf[8] + tb;
    float z = fmaxf(win[1][wi + 1], a);
    if (wi < 8) o0[wi] = (bf16)z; else o1[wi - 8] = (bf16)z;
  }
  bf16* dst = (ch < KC_) ? (kf + ((size_t)(b * KC_ + ch)) * N_)
                         : (vfc + ((size_t)(b * KC_ + ch - KC_)) * N_);
  *(bf16x8*)(dst + (size_t)r * 64 + ws0) = o0;
  *(bf16x8*)(dst + (size_t)r * 64 + ws0 + 8) = o1;
}

// ---------------- k2b: vf [B,256,N] -> [B,N,256] bf16 transpose --------------
__global__ __launch_bounds__(256) void k2b_transpose(const bf16* __restrict__ vfc,
                                                     bf16* __restrict__ vfh)
{
  __shared__ uint32_t t[64 * 64];
  int nt = blockIdx.x, vt = blockIdx.y, b = blockIdx.z;
  int tid = threadIdx.x;
  const uint16_t* src = (const uint16_t*)(vfc + ((size_t)(b * KC_ + vt * 64)) * N_ + nt * 64);
#pragma unroll
  for (int i = 0; i < 2; ++i) {
    int u = tid + i * 256;
    int v = u >> 3, c8 = u & 7;
    u16x8 d = *(const u16x8*)(src + (size_t)v * N_ + c8 * 8);
#pragma unroll
    for (int j = 0; j < 8; ++j) {
      int n = c8 * 8 + j;
      t[v * 64 + (n ^ (v & 31))] = d[j];
    }
  }
  __syncthreads();
  uint16_t* dst = (uint16_t*)(vfh + ((size_t)b * N_ + nt * 64) * KC_ + vt * 64);
#pragma unroll
  for (int i = 0; i < 2; ++i) {
    int u = tid + i * 256;
    int nl = u >> 3, v8 = u & 7;
    u16x8 o;
#pragma unroll
    for (int j = 0; j < 8; ++j) {
      int v = v8 * 8 + j;
      o[j] = (uint16_t)t[v * 64 + (nl ^ (v & 31))];
    }
    *(u16x8*)(dst + (size_t)nl * KC_ + v8 * 8) = o;
  }
}

// ------- softmax: sum 8 split-K partials, then softmax rows -> P bf16 --------
__global__ __launch_bounds__(256) void softmax_k(const float* __restrict__ simp,
                                                 bf16* __restrict__ P)
{
  int row = blockIdx.x * 4 + (threadIdx.x >> 6);   // row = b*256 + v
  int b = row >> 8, v = row & 255;
  int lane = threadIdx.x & 63;
  const float* base = simp + (size_t)b * 8 * 65536 + (size_t)v * 256 + lane * 4;
  f32x4 s = 0.f;
#pragma unroll
  for (int ks = 0; ks < 8; ++ks)
    s += *reinterpret_cast<const f32x4*>(base + (size_t)ks * 65536);
  float mx = fmaxf(fmaxf(s[0], s[1]), fmaxf(s[2], s[3]));
#pragma unroll
  for (int sh = 32; sh; sh >>= 1) mx = fmaxf(mx, __shfl_xor(mx, sh));
  float a0 = __expf(s[0] - mx), a1 = __expf(s[1] - mx);
  float a2 = __expf(s[2] - mx), a3 = __expf(s[3] - mx);
  float sm = a0 + a1 + a2 + a3;
#pragma unroll
  for (int sh = 32; sh; sh >>= 1) sm += __shfl_xor(sm, sh);
  float inv = 1.0f / sm;
  bf16x4 o;
  o[0] = (bf16)(a0 * inv); o[1] = (bf16)(a1 * inv);
  o[2] = (bf16)(a2 * inv); o[3] = (bf16)(a3 * inv);
  *(bf16x4*)(P + (size_t)row * 256 + lane * 4) = o;
}

// ---------------- host launch ------------------------------------------------
extern "C" void kernel_launch(void* const* d_in, const int* in_sizes, int n_in,
                              void* d_out, int out_size, void* d_ws, size_t ws_size,
                              hipStream_t stream) {
  const float* x      = (const float*)d_in[0];
  const float* fk_cw  = (const float*)d_in[1];
  const float* fk_cb  = (const float*)d_in[2];
  const float* fk_bg  = (const float*)d_in[3];
  const float* fk_bb  = (const float*)d_in[4];
  const float* fk_bm  = (const float*)d_in[5];
  const float* fk_bv  = (const float*)d_in[6];
  const float* fk_dw  = (const float*)d_in[7];
  const float* fk_db  = (const float*)d_in[8];
  const float* fk_dg  = (const float*)d_in[9];
  const float* fk_dbb = (const float*)d_in[10];
  const float* fk_dm  = (const float*)d_in[11];
  const float* fk_dv  = (const float*)d_in[12];
  const float* fv_cw  = (const float*)d_in[13];
  const float* fv_cb  = (const float*)d_in[14];
  const float* fv_bg  = (const float*)d_in[15];
  const float* fv_bb  = (const float*)d_in[16];
  const float* fv_bm  = (const float*)d_in[17];
  const float* fv_bv  = (const float*)d_in[18];
  const float* fv_dw  = (const float*)d_in[19];
  const float* fv_db  = (const float*)d_in[20];
  const float* fv_dg  = (const float*)d_in[21];
  const float* fv_dbb = (const float*)d_in[22];
  const float* fv_dm  = (const float*)d_in[23];
  const float* fv_dv  = (const float*)d_in[24];
  const float* w_w    = (const float*)d_in[25];
  const float* w_b    = (const float*)d_in[26];

  char* wsp = (char*)d_ws;
  size_t off = 0;
  auto take = [&](size_t bytes) -> void* {
    void* p = wsp + off;
    off += (bytes + 255) & ~(size_t)255;
    return p;
  };
  bf16*  xb    = (bf16*) take((size_t)B_ * N_ * C_ * 2);      // 33.6 MB  x NHWC bf16 (later reused as vfh)
  bf16*  y     = (bf16*) take((size_t)B_ * OC2_ * N_ * 2);    // 33.6 MB  conv+BN out NCHW
  bf16*  kf    = (bf16*) take((size_t)B_ * KC_ * N_ * 2);     // 16.8 MB  key-branch NCHW
  bf16*  vfc   = (bf16*) take((size_t)B_ * KC_ * N_ * 2);     // 16.8 MB  value-branch NCHW
  float* simp  = (float*)take((size_t)B_ * 8 * 65536 * 4);    // 16.8 MB  split-K partials
  bf16*  P     = (bf16*) take((size_t)B_ * KC_ * KC_ * 2);    //  1.0 MB
  bf16*  MmT   = (bf16*) take((size_t)B_ * 512 * KC_ * 2);    //  2.1 MB  (P @ Ww^T)^T
  bf16*  Wcat  = (bf16*) take((size_t)512 * 512 * 2);
  bf16*  Ww    = (bf16*) take((size_t)512 * 256 * 2);
  float* sconv = (float*)take(512 * 4);
  float* tconv = (float*)take(512 * 4);
  float* wdw9  = (float*)take(512 * 9 * 4);
  float* tdwb  = (float*)take(512 * 4);
  // vfh aliases xb: xb is only read by the branch-conv GEMM; vfh is first
  // written by k2b_transpose, which runs strictly after that GEMM.
  bf16*  vfh   = xb;                                          // 16.8 MB  value-branch NHWC

  prep_kernel<<<1540, 256, 0, stream>>>(
      fk_cw, fk_cb, fk_bg, fk_bb, fk_bm, fk_bv, fk_dw, fk_db, fk_dg, fk_dbb, fk_dm, fk_dv,
      fv_cw, fv_cb, fv_bg, fv_bb, fv_bm, fv_bv, fv_dw, fv_db, fv_dg, fv_dbb, fv_dm, fv_dv,
      w_w, Wcat, Ww, sconv, tconv, wdw9, tdwb);

  k0_transpose<<<dim3(64, 8, 8), 256, 0, stream>>>(x, xb);

  // y[b,oc,n] = BN(Wcat @ xb) : M=512 oc, N=4096 n, K=512 c
  gemm_tn<0, 4, 32, 1, 512><<<dim3(1024), 256, 0, stream>>>(
      Wcat, 512, 0, xb, 512, (size_t)N_ * C_, y, 4096, (size_t)OC2_ * N_, sconv, tconv);

  k2_dwfrelu<<<dim3(512, 8), 256, 0, stream>>>(y, wdw9, tdwb, kf, vfc);
  k2b_transpose<<<dim3(64, 4, 8), 256, 0, stream>>>(vfc, vfh);

  // sim partials: simp[b*8+ks][v][k] = (vf . kf over n-chunk)/64, split-K=8
  gemm_tn<4, 2, 2, 8, 512><<<dim3(256), 256, 0, stream>>>(
      vfc, 4096, (size_t)KC_ * N_, kf, 4096, (size_t)KC_ * N_,
      simp, 256, 65536, nullptr, nullptr);

  softmax_k<<<dim3(512), 256, 0, stream>>>(simp, P);

  // MmT[b,o,v] = sum_k Ww[o,k] P[v,k]
  gemm_tn<2, 4, 2, 1, 256><<<dim3(64), 256, 0, stream>>>(
      Ww, 256, 0, P, 256, (size_t)KC_ * KC_,
      MmT, 256, (size_t)512 * KC_, nullptr, nullptr);

  // out[b,o,n] = sum_v MmT[o,v] vfh[n,v] + w_b[o]
  gemm_tn<3, 4, 32, 1, 256><<<dim3(1024), 256, 0, stream>>>(
      MmT, 256, (size_t)512 * KC_, vfh, 256, (size_t)N_ * KC_,
      (float*)d_out, 4096, (size_t)512 * N_, w_b, nullptr);
}